// Round 9
// baseline (506.237 us; speedup 1.0000x reference)
//
#include <hip/hip_runtime.h>

// Problem dims
#define B_  32
#define N_  1024
#define E_  1024
#define H_  8
#define D_  128
#define MID_ 64
#define NT_  32        // n-tiles for score+pool (32 rows each)
#define TR_  32        // rows per tile
#define NSP_ 32        // v2-pool splits (32 rows each)

// Journal (counter-backed lessons):
//  R3: never scale occupancy by replaying the same stream.
//  R4: never scale same-destination atomic writers (HBM RMW explosion).
//  R5: VGPR_Count=64 on a register-hungry kernel = spill to scratch.
//  R6: __launch_bounds__(X,4) forces the 64-VGPR tier -> spill.
//  R7: plain bounds: VGPR 72, bytes = ideal; ~80% of scorepool time is
//      stall (barriers + idle-wave finalize), not bytes or VALU.
//  R8: barrier halving was cancelled by VGPR 108 occupancy-tier slip;
//      16-row pool splits = too little work per block. Total 398 while
//      floor arithmetic says ~50: THREE serial latency-bound kernels.
//  => R9: overlap key & value2 streams in ONE grid; 1 barrier/subtile
//     (all-thread redundant finalize fused into outer product).

// ---------------------------------------------------------------------------
// k_qkproj: per (b,h), 256 thr. Q = query[b]·Wq_h^T + bq; qb = Q·bk_h;
// qk = Q·Wk_h.  Wq/Wk h-slices are L3-hot after first touch (8 MB total).
// ---------------------------------------------------------------------------
__global__ __launch_bounds__(256) void k_qkproj(
        const float* __restrict__ query, const float* __restrict__ Wq,
        const float* __restrict__ bq, const float* __restrict__ Wk,
        const float* __restrict__ bk, float* __restrict__ qk,
        float* __restrict__ qb)
{
    const int bh = blockIdx.x;
    const int b = bh >> 3, h = bh & 7;
    const int t = threadIdx.x;
    const int l = t & 63, w = t >> 6;       // 4 waves
    const int rg = l >> 4, cl = l & 15;     // 4 row-groups x 16 lanes

    __shared__ __align__(16) float qsh[E_];
    __shared__ float Qs[D_];
    __shared__ float red[4];

    ((float4*)qsh)[t] = ((const float4*)(query + (size_t)b * E_))[t];
    __syncthreads();

    // phase A: Q[d] = query[b]·Wq_row(h*D+d) + bq, 16 lanes per row
    const float4* qsh4 = (const float4*)qsh;
    float qbacc = 0.f;
    #pragma unroll 2
    for (int p = 0; p < 8; ++p) {
        const int d = p * 16 + w * 4 + rg;
        const int row = h * D_ + d;
        const float4* wr = (const float4*)(Wq + (size_t)row * E_);
        float acc = 0.f;
        #pragma unroll 4
        for (int i = 0; i < 16; ++i) {
            float4 wv = wr[cl + i * 16];
            float4 qv = qsh4[cl + i * 16];
            acc += wv.x * qv.x + wv.y * qv.y + wv.z * qv.z + wv.w * qv.w;
        }
        #pragma unroll
        for (int off = 8; off; off >>= 1) acc += __shfl_xor(acc, off);
        if (cl == 0) {
            float q = acc + bq[row];
            Qs[d] = q;
            qbacc += q * bk[row];
        }
    }
    #pragma unroll
    for (int off = 32; off; off >>= 1) qbacc += __shfl_down(qbacc, off);
    if (l == 0) red[w] = qbacc;
    __syncthreads();
    if (t == 0) qb[bh] = red[0] + red[1] + red[2] + red[3];

    // phase B: qk row, thread owns 4 e's (coalesced per d-iteration)
    const int e0 = t * 4;
    float4 a = make_float4(0.f, 0.f, 0.f, 0.f);
    const float* wkb = Wk + (size_t)(h * D_) * E_ + e0;
    #pragma unroll 8
    for (int d = 0; d < D_; ++d) {
        float Qd = Qs[d];
        float4 wv = *(const float4*)(wkb + (size_t)d * E_);
        a.x += Qd * wv.x; a.y += Qd * wv.y; a.z += Qd * wv.z; a.w += Qd * wv.w;
    }
    *(float4*)(qk + (size_t)bh * E_ + e0) = a;
}

// ---------------------------------------------------------------------------
// k_main: 2048 blocks, 256 thr.
//   even blocks: score+pool tile (key stream);  odd blocks: v2 pool split
//   (value2 stream). Interleaved so every CU/XCD co-schedules both streams —
//   pool fills score's stall slack.
//
//   Score tile (TR=32, 4 subtiles of 8 rows, ONE barrier per subtile):
//     dots: p[h] = kv·qkr[h] per row, 6-step butterfly; lane0/wave writes
//           part[w][r][h].  barrier.
//     finalize+outer FUSED: every thread redundantly sums part[0..3][r][h]
//       (broadcast b128 LDS reads, conflict-free), forms s, accumulates
//       pacc[h] += s[h]*kv[r], reloads kv[r] for the next subtile right
//       after its last use. No second barrier, no idle-wave phase.
//     ssum: every thread holds identical per-(h) tile sums -> thread 0
//       does 8 compile-time-indexed atomics.
// ---------------------------------------------------------------------------
__global__ __launch_bounds__(256) void k_main(
        const float* __restrict__ key, const float* __restrict__ qk,
        const float* __restrict__ qb, float* __restrict__ PPpart,
        float* __restrict__ ssum,
        const float* __restrict__ value2, const int* __restrict__ mask,
        float* __restrict__ P2p)
{
    const int t = threadIdx.x;

    __shared__ __align__(16) float part[4][8][8];   // [wave][row][h], 1 KB
    __shared__ int rows[NSP_];
    __shared__ int nrows;

    if ((blockIdx.x & 1) == 0) {
        // ================= score+pool tile =================
        const int si = blockIdx.x >> 1;         // [0,1024)
        const int tile = si >> 5, b = si & 31;
        const int w = t >> 6, l = t & 63;

        const float scale = 0.08838834764831845f;  // 1/sqrt(128)
        const float* keyb = key + ((size_t)b * N_ + (size_t)tile * TR_) * E_;

        // qb for all 8 heads (contiguous, 16B-aligned)
        const float4 qb0 = ((const float4*)(qb + b * 8))[0];
        const float4 qb1 = ((const float4*)(qb + b * 8))[1];

        float4 qkr[8];
        #pragma unroll
        for (int h = 0; h < H_; ++h)
            qkr[h] = ((const float4*)(qk + (size_t)(b * 8 + h) * E_))[t];

        float4 pacc[8];
        #pragma unroll
        for (int h = 0; h < 8; ++h) pacc[h] = make_float4(0.f, 0.f, 0.f, 0.f);

        float4 tsh0 = make_float4(0.f, 0.f, 0.f, 0.f);   // per-h s sums
        float4 tsh1 = make_float4(0.f, 0.f, 0.f, 0.f);

        float4 kv[8];
        #pragma unroll
        for (int r = 0; r < 8; ++r)
            kv[r] = ((const float4*)(keyb + (size_t)r * E_))[t];

        for (int st = 0; st < 4; ++st) {
            // --- dots: 8 rows x 8 heads, butterfly over the wave
            #pragma unroll
            for (int r = 0; r < 8; ++r) {
                float p[8];
                #pragma unroll
                for (int h = 0; h < 8; ++h)
                    p[h] = qkr[h].x * kv[r].x + qkr[h].y * kv[r].y
                         + qkr[h].z * kv[r].z + qkr[h].w * kv[r].w;
                #pragma unroll
                for (int off = 32; off; off >>= 1) {
                    #pragma unroll
                    for (int h = 0; h < 8; ++h)
                        p[h] += __shfl_xor(p[h], off);
                }
                if (l == 0) {
                    *(float4*)&part[w][r][0] = make_float4(p[0], p[1], p[2], p[3]);
                    *(float4*)&part[w][r][4] = make_float4(p[4], p[5], p[6], p[7]);
                }
            }
            __syncthreads();
            // --- finalize + outer, fused; per-row kv reload staggered
            #pragma unroll
            for (int r = 0; r < 8; ++r) {
                float4 a0 = *(const float4*)&part[0][r][0];
                float4 a1 = *(const float4*)&part[1][r][0];
                float4 a2 = *(const float4*)&part[2][r][0];
                float4 a3 = *(const float4*)&part[3][r][0];
                float4 b0 = *(const float4*)&part[0][r][4];
                float4 b1 = *(const float4*)&part[1][r][4];
                float4 b2 = *(const float4*)&part[2][r][4];
                float4 b3 = *(const float4*)&part[3][r][4];
                float4 sA, sB;
                sA.x = (a0.x + a1.x + a2.x + a3.x + qb0.x) * scale;
                sA.y = (a0.y + a1.y + a2.y + a3.y + qb0.y) * scale;
                sA.z = (a0.z + a1.z + a2.z + a3.z + qb0.z) * scale;
                sA.w = (a0.w + a1.w + a2.w + a3.w + qb0.w) * scale;
                sB.x = (b0.x + b1.x + b2.x + b3.x + qb1.x) * scale;
                sB.y = (b0.y + b1.y + b2.y + b3.y + qb1.y) * scale;
                sB.z = (b0.z + b1.z + b2.z + b3.z + qb1.z) * scale;
                sB.w = (b0.w + b1.w + b2.w + b3.w + qb1.w) * scale;
                tsh0.x += sA.x; tsh0.y += sA.y; tsh0.z += sA.z; tsh0.w += sA.w;
                tsh1.x += sB.x; tsh1.y += sB.y; tsh1.z += sB.z; tsh1.w += sB.w;
                const float4 k4 = kv[r];
                pacc[0].x += sA.x * k4.x; pacc[0].y += sA.x * k4.y;
                pacc[0].z += sA.x * k4.z; pacc[0].w += sA.x * k4.w;
                pacc[1].x += sA.y * k4.x; pacc[1].y += sA.y * k4.y;
                pacc[1].z += sA.y * k4.z; pacc[1].w += sA.y * k4.w;
                pacc[2].x += sA.z * k4.x; pacc[2].y += sA.z * k4.y;
                pacc[2].z += sA.z * k4.z; pacc[2].w += sA.z * k4.w;
                pacc[3].x += sA.w * k4.x; pacc[3].y += sA.w * k4.y;
                pacc[3].z += sA.w * k4.z; pacc[3].w += sA.w * k4.w;
                pacc[4].x += sB.x * k4.x; pacc[4].y += sB.x * k4.y;
                pacc[4].z += sB.x * k4.z; pacc[4].w += sB.x * k4.w;
                pacc[5].x += sB.y * k4.x; pacc[5].y += sB.y * k4.y;
                pacc[5].z += sB.y * k4.z; pacc[5].w += sB.y * k4.w;
                pacc[6].x += sB.z * k4.x; pacc[6].y += sB.z * k4.y;
                pacc[6].z += sB.z * k4.z; pacc[6].w += sB.z * k4.w;
                pacc[7].x += sB.w * k4.x; pacc[7].y += sB.w * k4.y;
                pacc[7].z += sB.w * k4.z; pacc[7].w += sB.w * k4.w;
                if (st < 3)   // reload this row's kv right after last use
                    kv[r] = ((const float4*)(keyb
                                + (size_t)((st + 1) * 8 + r) * E_))[t];
            }
            if (st < 3) __syncthreads();   // part reused next subtile
        }

        // ssum: every thread holds identical tile sums; thread 0 commits
        if (t == 0) {
            atomicAdd(&ssum[b * 8 + 0], tsh0.x);
            atomicAdd(&ssum[b * 8 + 1], tsh0.y);
            atomicAdd(&ssum[b * 8 + 2], tsh0.z);
            atomicAdd(&ssum[b * 8 + 3], tsh0.w);
            atomicAdd(&ssum[b * 8 + 4], tsh1.x);
            atomicAdd(&ssum[b * 8 + 5], tsh1.y);
            atomicAdd(&ssum[b * 8 + 6], tsh1.z);
            atomicAdd(&ssum[b * 8 + 7], tsh1.w);
        }

        // PPpart: one plain float4 store per (h, e-chunk)
        #pragma unroll
        for (int h = 0; h < 8; ++h) {
            ((float4*)(PPpart
                + (((size_t)(b * H_ + h)) * NT_ + tile) * E_))[t] = pacc[h];
        }
    } else {
        // ================= v2 pooling split =================
        const int pi = blockIdx.x >> 1;         // [0,1024)
        const int b = pi & 31, sp = pi >> 5;    // 32 splits of 32 rows
        const int e0 = t * 4;
        const int n0 = sp * NSP_;

        if (t == 0) nrows = 0;
        __syncthreads();
        if (t < NSP_) {
            if (mask[b * N_ + n0 + t]) {
                int i2 = atomicAdd(&nrows, 1);
                rows[i2] = t;
            }
        }
        __syncthreads();
        const int nr = nrows;

        float a0 = 0.f, a1 = 0.f, a2 = 0.f, a3 = 0.f;
        const float* vb = value2 + ((size_t)(b * N_ + n0)) * E_ + e0;
        #pragma unroll 4
        for (int i = 0; i < nr; ++i) {
            float4 v = *(const float4*)(vb + (size_t)rows[i] * E_);
            a0 += v.x; a1 += v.y; a2 += v.z; a3 += v.w;
        }
        float* dst = P2p + ((size_t)(sp & 7) * B_ + b) * E_ + e0;
        atomicAdd(dst + 0, a0); atomicAdd(dst + 1, a1);
        atomicAdd(dst + 2, a2); atomicAdd(dst + 3, a3);
    }
}

// ---------------------------------------------------------------------------
// k_tail (fused reduce + Wv dots + epilogue): per bh, 512 threads.
// ---------------------------------------------------------------------------
__global__ __launch_bounds__(512) void k_tail(
        const float* __restrict__ PPpart, const float* __restrict__ P2p,
        const float* __restrict__ ssumg, const int* __restrict__ mask,
        const float* __restrict__ Wv, const float* __restrict__ bv,
        const float* __restrict__ Wb, const float* __restrict__ bb,
        const float* __restrict__ Wl2, const float* __restrict__ bl2,
        const float* __restrict__ value1, float* __restrict__ out)
{
    const int bh = blockIdx.x, b = bh >> 3, h = bh & 7;
    const int t = threadIdx.x;
    const int l = t & 63, w = t >> 6;       // 8 waves
    const int rg = l >> 4, cl = l & 15;     // 4 row-groups x 16 lanes

    __shared__ __align__(16) float ph[2][E_];
    __shared__ __align__(16) float pooled[E_];
    __shared__ __align__(16) float pool2[E_];
    __shared__ float attA_s[D_];
    __shared__ float attV_s[D_];
    __shared__ float att[D_];
    __shared__ float hv[MID_];
    __shared__ float red2[2];
    __shared__ float cnt_s;

    // stage 1: reduce PPpart over NT tiles (two 16-tile halves)
    {
        const int c4 = t & 255, half = t >> 8;
        const float4* pp = (const float4*)(PPpart + (size_t)bh * NT_ * E_);
        float4 s = make_float4(0.f, 0.f, 0.f, 0.f);
        #pragma unroll 4
        for (int j = 0; j < 16; ++j) {
            float4 v = pp[(half * 16 + j) * 256 + c4];
            s.x += v.x; s.y += v.y; s.z += v.z; s.w += v.w;
        }
        ((float4*)&ph[half][0])[c4] = s;
    }
    __syncthreads();
    if (t < 256) {
        float4 p0 = ((const float4*)&ph[0][0])[t];
        float4 p1 = ((const float4*)&ph[1][0])[t];
        ((float4*)pooled)[t] = make_float4(p0.x + p1.x, p0.y + p1.y,
                                           p0.z + p1.z, p0.w + p1.w);
        float4 q = make_float4(0.f, 0.f, 0.f, 0.f);
        #pragma unroll
        for (int k2 = 0; k2 < 8; ++k2) {
            float4 v = ((const float4*)(P2p + ((size_t)k2 * B_ + b) * E_))[t];
            q.x += v.x; q.y += v.y; q.z += v.z; q.w += v.w;
        }
        ((float4*)pool2)[t] = q;
    }
    __syncthreads();

    // stage 2: Wv dots — 8 waves x 4 passes x 4 rg = 128 d
    const float4* pooled4 = (const float4*)pooled;
    const float4* pool24  = (const float4*)pool2;
    #pragma unroll
    for (int p = 0; p < 4; ++p) {
        const int d = p * 32 + w * 4 + rg;
        const float4* wvr = (const float4*)(Wv + (size_t)(h * D_ + d) * E_);
        float pA = 0.f, pV = 0.f;
        #pragma unroll 4
        for (int i = 0; i < 16; ++i) {
            float4 wv4 = wvr[cl + i * 16];
            float4 pa = pooled4[cl + i * 16];
            float4 pb = pool24[cl + i * 16];
            pA += wv4.x * pa.x + wv4.y * pa.y + wv4.z * pa.z + wv4.w * pa.w;
            pV += wv4.x * pb.x + wv4.y * pb.y + wv4.z * pb.z + wv4.w * pb.w;
        }
        #pragma unroll
        for (int off = 8; off; off >>= 1) {
            pA += __shfl_xor(pA, off);
            pV += __shfl_xor(pV, off);
        }
        if (cl == 0) { attA_s[d] = pA; attV_s[d] = pV; }
    }
    __syncthreads();

    // stage 3: epilogue
    if (t < 128) {
        int ci = 0;
        #pragma unroll
        for (int i = 0; i < 8; ++i) ci += mask[b * N_ + t + i * 128];
        float cf = (float)ci;
        #pragma unroll
        for (int off = 32; off; off >>= 1) cf += __shfl_down(cf, off);
        if ((t & 63) == 0) red2[t >> 6] = cf;
        const float ss = ssumg[bh];
        att[t] = attA_s[t] + ss * bv[h * D_ + t];
    }
    __syncthreads();
    if (t == 0) cnt_s = red2[0] + red2[1];
    if (t < MID_) {
        float a = bb[t];
        #pragma unroll 4
        for (int d2 = 0; d2 < D_; ++d2) a += att[d2] * Wb[t * D_ + d2];
        hv[t] = fmaxf(a, 0.f);
    }
    __syncthreads();
    if (t < 128) {
        float z = bl2[t];
        #pragma unroll
        for (int m = 0; m < MID_; ++m) z += hv[m] * Wl2[t * MID_ + m];
        float alphac = 1.f / (1.f + expf(-z));
        const float bvd = bv[h * D_ + t];
        float v2a = attV_s[t] / cnt_s + bvd;
        out[(size_t)b * E_ + h * D_ + t] =
            value1[(size_t)b * E_ + h * D_ + t] * v2a * alphac;
    }
}

// ---------------------------------------------------------------------------
extern "C" void kernel_launch(void* const* d_in, const int* in_sizes, int n_in,
                              void* d_out, int out_size, void* d_ws, size_t ws_size,
                              hipStream_t stream)
{
    const float* query  = (const float*)d_in[0];
    const float* key    = (const float*)d_in[1];
    const int*   mask   = (const int*)d_in[2];
    const float* value1 = (const float*)d_in[3];
    const float* value2 = (const float*)d_in[4];
    const float* Wq  = (const float*)d_in[5];
    const float* bq  = (const float*)d_in[6];
    const float* Wk  = (const float*)d_in[7];
    const float* bk  = (const float*)d_in[8];
    const float* Wv  = (const float*)d_in[9];
    const float* bv  = (const float*)d_in[10];
    const float* Wb  = (const float*)d_in[11];
    const float* bb  = (const float*)d_in[12];
    // d_in[13] = Wl, d_in[14] = bl: eliminated (softmax of uniform = mask/cnt)
    const float* Wl2 = (const float*)d_in[15];
    const float* bl2 = (const float*)d_in[16];
    float* out = (float*)d_out;

    // workspace layout (bytes), total ~35 MB
    char* ws = (char*)d_ws;
    const size_t SZ_PPP = (size_t)B_ * H_ * NT_ * E_ * 4;     // PPpart: 32 MB
    const size_t SZ_P2P = (size_t)8 * B_ * E_ * 4;            // P2p: 1 MB
    const size_t OFF_P2P = SZ_PPP;
    const size_t OFF_SS  = OFF_P2P + SZ_P2P;                  // ssum: 1 KB
    const size_t OFF_QB  = OFF_SS + 1024;                     // qb: 1 KB
    const size_t OFF_QK  = OFF_QB + 1024;                     // qk: 1 MB
    float* PPpart = (float*)(ws);
    float* P2p  = (float*)(ws + OFF_P2P);
    float* ssum = (float*)(ws + OFF_SS);
    float* qb   = (float*)(ws + OFF_QB);
    float* qk   = (float*)(ws + OFF_QK);

    // zero the atomic-accumulated region (P2p + ssum); PPpart is fully
    // overwritten by plain stores. stream-ordered, capture-safe
    hipMemsetAsync(ws + OFF_P2P, 0, SZ_P2P + 1024, stream);

    hipLaunchKernelGGL(k_qkproj, dim3(B_ * H_), dim3(256), 0, stream,
                       query, Wq, bq, Wk, bk, qk, qb);
    hipLaunchKernelGGL(k_main, dim3(2 * NT_ * B_), dim3(256), 0, stream,
                       key, qk, qb, PPpart, ssum, value2, mask, P2p);
    hipLaunchKernelGGL(k_tail, dim3(B_ * H_), dim3(512), 0, stream,
                       PPpart, P2p, ssum, mask, Wv, bv, Wb, bb, Wl2, bl2,
                       value1, out);
}

// Round 10
// 437.497 us; speedup vs baseline: 1.1571x; 1.1571x over previous
//
#include <hip/hip_runtime.h>

// Problem dims
#define B_  32
#define N_  1024
#define E_  1024
#define H_  8
#define D_  128
#define MID_ 64
#define NT_  32        // n-tiles for score+pool (32 rows each)
#define TR_  32        // rows per tile
#define NSP_ 32        // v2-pool split rows

// Journal (counter-backed lessons):
//  R3: never scale occupancy by replaying the same stream.
//  R4: never scale same-destination atomic writers (HBM RMW explosion).
//  R5: VGPR=64 on a register-hungry kernel = spill to scratch.
//  R6: __launch_bounds__(X,4) forces the 64-VGPR tier -> spill.
//  R7: plain bounds -> VGPR 72, bytes ideal, 92us scorepool (best).
//  R8: 8-row subtiles -> VGPR 108, occupancy tier slip, no win.
//  R9: all-thread redundant finalize+outer -> VGPR 204, occ 6.8%, 267us.
//      Run live-set arithmetic BEFORE benching a rewrite. R7 shape
//      (lane0->LDS->64-thread finalize) is the VGPR-feasible one.
//  Attribution bound (top-5 semantics): every non-scorepool dispatch in
//  R7/R8 was <92/96us; analytic sizes put red/final at <=5us. A stable
//  ~200-240us fixed cost (residual 240-310 across 3/4/5-kernel builds)
//  dominates the non-scorepool time. => minimize SUM of kernel times.
//  R10: R7-scorepool verbatim on even blocks || v2-pool on odd blocks
//  (R9's interleave was sound; its score-branch registers were not).

// ---------------------------------------------------------------------------
// k_qkproj: per (b,h), 256 thr. Q = query[b]·Wq_h^T + bq; qb = Q·bk_h;
// qk = Q·Wk_h.
// ---------------------------------------------------------------------------
__global__ __launch_bounds__(256) void k_qkproj(
        const float* __restrict__ query, const float* __restrict__ Wq,
        const float* __restrict__ bq, const float* __restrict__ Wk,
        const float* __restrict__ bk, float* __restrict__ qk,
        float* __restrict__ qb)
{
    const int bh = blockIdx.x;
    const int b = bh >> 3, h = bh & 7;
    const int t = threadIdx.x;
    const int l = t & 63, w = t >> 6;       // 4 waves
    const int rg = l >> 4, cl = l & 15;     // 4 row-groups x 16 lanes

    __shared__ __align__(16) float qsh[E_];
    __shared__ float Qs[D_];
    __shared__ float red[4];

    ((float4*)qsh)[t] = ((const float4*)(query + (size_t)b * E_))[t];
    __syncthreads();

    // phase A: Q[d] = query[b]·Wq_row(h*D+d) + bq, 16 lanes per row
    const float4* qsh4 = (const float4*)qsh;
    float qbacc = 0.f;
    #pragma unroll 2
    for (int p = 0; p < 8; ++p) {
        const int d = p * 16 + w * 4 + rg;
        const int row = h * D_ + d;
        const float4* wr = (const float4*)(Wq + (size_t)row * E_);
        float acc = 0.f;
        #pragma unroll 4
        for (int i = 0; i < 16; ++i) {
            float4 wv = wr[cl + i * 16];
            float4 qv = qsh4[cl + i * 16];
            acc += wv.x * qv.x + wv.y * qv.y + wv.z * qv.z + wv.w * qv.w;
        }
        #pragma unroll
        for (int off = 8; off; off >>= 1) acc += __shfl_xor(acc, off);
        if (cl == 0) {
            float q = acc + bq[row];
            Qs[d] = q;
            qbacc += q * bk[row];
        }
    }
    #pragma unroll
    for (int off = 32; off; off >>= 1) qbacc += __shfl_down(qbacc, off);
    if (l == 0) red[w] = qbacc;
    __syncthreads();
    if (t == 0) qb[bh] = red[0] + red[1] + red[2] + red[3];

    // phase B: qk row, thread owns 4 e's (coalesced per d-iteration)
    const int e0 = t * 4;
    float4 a = make_float4(0.f, 0.f, 0.f, 0.f);
    const float* wkb = Wk + (size_t)(h * D_) * E_ + e0;
    #pragma unroll 8
    for (int d = 0; d < D_; ++d) {
        float Qd = Qs[d];
        float4 wv = *(const float4*)(wkb + (size_t)d * E_);
        a.x += Qd * wv.x; a.y += Qd * wv.y; a.z += Qd * wv.z; a.w += Qd * wv.w;
    }
    *(float4*)(qk + (size_t)bh * E_ + e0) = a;
}

// ---------------------------------------------------------------------------
// k_main: 2048 blocks, 256 thr.
//   EVEN blocks: R7 scorepool tile VERBATIM (92us, VGPR 72 proven):
//     32-row tile, 8 subtiles of 4 rows; dots -> lane0 writes part ->
//     barrier -> 64-thread finalize -> barrier -> outer with same kv regs;
//     kn prefetch issued before the barriers. Key read exactly once.
//   ODD blocks: v2-pool 32-row split (value2 stream) — fills the score
//     blocks' measured ~80% stall slack; P2p[8] partials (4 contenders).
// ---------------------------------------------------------------------------
__global__ __launch_bounds__(256) void k_main(
        const float* __restrict__ key, const float* __restrict__ qk,
        const float* __restrict__ qb, float* __restrict__ PPpart,
        float* __restrict__ ssum,
        const float* __restrict__ value2, const int* __restrict__ mask,
        float* __restrict__ P2p)
{
    const int t = threadIdx.x;

    __shared__ __align__(16) float part[4][4][8];   // [wave][r][h], 512 B
    __shared__ __align__(16) float sfin[4][8];      // [r][h], 128 B
    __shared__ int rows[NSP_];
    __shared__ int nrows;

    if ((blockIdx.x & 1) == 0) {
        // ================= score+pool tile (R7 verbatim) =================
        const int si = blockIdx.x >> 1;       // [0,1024)
        const int tile = si & 31, b = si >> 5;
        const int w = t >> 6, l = t & 63;

        const float scale = 0.08838834764831845f;  // 1/sqrt(128)
        const float* keyb = key + ((size_t)b * N_ + (size_t)tile * TR_) * E_;
        const float qbv = (t < 32) ? qb[b * 8 + (t & 7)] : 0.f;

        float4 qkr[8];
        #pragma unroll
        for (int h = 0; h < H_; ++h)
            qkr[h] = ((const float4*)(qk + (size_t)(b * 8 + h) * E_))[t];

        float4 pacc[8];
        #pragma unroll
        for (int h = 0; h < 8; ++h) pacc[h] = make_float4(0.f, 0.f, 0.f, 0.f);

        float ts = 0.f;

        float4 kv[4];
        #pragma unroll
        for (int r = 0; r < 4; ++r)
            kv[r] = ((const float4*)(keyb + (size_t)r * E_))[t];

        for (int st = 0; st < 8; ++st) {
            // --- dots for this sub-tile's 4 rows
            #pragma unroll
            for (int r = 0; r < 4; ++r) {
                float p[8];
                #pragma unroll
                for (int h = 0; h < 8; ++h)
                    p[h] = qkr[h].x * kv[r].x + qkr[h].y * kv[r].y
                         + qkr[h].z * kv[r].z + qkr[h].w * kv[r].w;
                #pragma unroll
                for (int off = 32; off; off >>= 1) {
                    #pragma unroll
                    for (int h = 0; h < 8; ++h)
                        p[h] += __shfl_xor(p[h], off);
                }
                if (l == 0) {
                    *(float4*)&part[w][r][0] = make_float4(p[0], p[1], p[2], p[3]);
                    *(float4*)&part[w][r][4] = make_float4(p[4], p[5], p[6], p[7]);
                }
            }
            // --- prefetch next sub-tile's rows (flies across the barriers)
            float4 kn[4];
            if (st < 7) {
                #pragma unroll
                for (int r = 0; r < 4; ++r)
                    kn[r] = ((const float4*)(keyb
                                + (size_t)((st + 1) * 4 + r) * E_))[t];
            }
            __syncthreads();
            // --- finalize s across the 4 waves (32 threads: r=t>>3, h=t&7)
            if (t < 32) {
                const int r = t >> 3, h = t & 7;
                float s = (part[0][r][h] + part[1][r][h]
                         + part[2][r][h] + part[3][r][h] + qbv) * scale;
                sfin[r][h] = s;
                ts += s;
            }
            __syncthreads();
            // --- outer product with the SAME kv registers
            #pragma unroll
            for (int r = 0; r < 4; ++r) {
                const float4 k4 = kv[r];
                const float4 sA = *(const float4*)&sfin[r][0];
                const float4 sB = *(const float4*)&sfin[r][4];
                pacc[0].x += sA.x * k4.x; pacc[0].y += sA.x * k4.y;
                pacc[0].z += sA.x * k4.z; pacc[0].w += sA.x * k4.w;
                pacc[1].x += sA.y * k4.x; pacc[1].y += sA.y * k4.y;
                pacc[1].z += sA.y * k4.z; pacc[1].w += sA.y * k4.w;
                pacc[2].x += sA.z * k4.x; pacc[2].y += sA.z * k4.y;
                pacc[2].z += sA.z * k4.z; pacc[2].w += sA.z * k4.w;
                pacc[3].x += sA.w * k4.x; pacc[3].y += sA.w * k4.y;
                pacc[3].z += sA.w * k4.z; pacc[3].w += sA.w * k4.w;
                pacc[4].x += sB.x * k4.x; pacc[4].y += sB.x * k4.y;
                pacc[4].z += sB.x * k4.z; pacc[4].w += sB.x * k4.w;
                pacc[5].x += sB.y * k4.x; pacc[5].y += sB.y * k4.y;
                pacc[5].z += sB.y * k4.z; pacc[5].w += sB.y * k4.w;
                pacc[6].x += sB.z * k4.x; pacc[6].y += sB.z * k4.y;
                pacc[6].z += sB.z * k4.z; pacc[6].w += sB.z * k4.w;
                pacc[7].x += sB.w * k4.x; pacc[7].y += sB.w * k4.y;
                pacc[7].z += sB.w * k4.z; pacc[7].w += sB.w * k4.w;
            }
            #pragma unroll
            for (int r = 0; r < 4; ++r) kv[r] = kn[r];
        }

        // --- ssum: fold r on the 32 finalize lanes, 8 atomics per tile
        if (t < 32) {
            float v = ts;
            v += __shfl_xor(v, 8);
            v += __shfl_xor(v, 16);
            if (l < 8) atomicAdd(&ssum[b * 8 + l], v);
        }

        // --- PPpart: one plain float4 store per (h, e-chunk)
        #pragma unroll
        for (int h = 0; h < 8; ++h) {
            ((float4*)(PPpart
                + (((size_t)(b * H_ + h)) * NT_ + tile) * E_))[t] = pacc[h];
        }
    } else {
        // ================= v2 pooling split =================
        const int pi = blockIdx.x >> 1;         // [0,1024)
        const int b = pi & 31, sp = pi >> 5;    // 32 splits of 32 rows
        const int e0 = t * 4;
        const int n0 = sp * NSP_;

        if (t == 0) nrows = 0;
        __syncthreads();
        if (t < NSP_) {
            if (mask[b * N_ + n0 + t]) {
                int i2 = atomicAdd(&nrows, 1);
                rows[i2] = t;
            }
        }
        __syncthreads();
        const int nr = nrows;

        float a0 = 0.f, a1 = 0.f, a2 = 0.f, a3 = 0.f;
        const float* vb = value2 + ((size_t)(b * N_ + n0)) * E_ + e0;
        #pragma unroll 4
        for (int i = 0; i < nr; ++i) {
            float4 v = *(const float4*)(vb + (size_t)rows[i] * E_);
            a0 += v.x; a1 += v.y; a2 += v.z; a3 += v.w;
        }
        float* dst = P2p + ((size_t)(sp & 7) * B_ + b) * E_ + e0;
        atomicAdd(dst + 0, a0); atomicAdd(dst + 1, a1);
        atomicAdd(dst + 2, a2); atomicAdd(dst + 3, a3);
    }
}

// ---------------------------------------------------------------------------
// k_tail (fused reduce + Wv dots + epilogue): per bh, 512 threads.
// ---------------------------------------------------------------------------
__global__ __launch_bounds__(512) void k_tail(
        const float* __restrict__ PPpart, const float* __restrict__ P2p,
        const float* __restrict__ ssumg, const int* __restrict__ mask,
        const float* __restrict__ Wv, const float* __restrict__ bv,
        const float* __restrict__ Wb, const float* __restrict__ bb,
        const float* __restrict__ Wl2, const float* __restrict__ bl2,
        const float* __restrict__ value1, float* __restrict__ out)
{
    const int bh = blockIdx.x, b = bh >> 3, h = bh & 7;
    const int t = threadIdx.x;
    const int l = t & 63, w = t >> 6;       // 8 waves
    const int rg = l >> 4, cl = l & 15;     // 4 row-groups x 16 lanes

    __shared__ __align__(16) float ph[2][E_];
    __shared__ __align__(16) float pooled[E_];
    __shared__ __align__(16) float pool2[E_];
    __shared__ float attA_s[D_];
    __shared__ float attV_s[D_];
    __shared__ float att[D_];
    __shared__ float hv[MID_];
    __shared__ float red2[2];
    __shared__ float cnt_s;

    // stage 1: reduce PPpart over NT tiles (two 16-tile halves)
    {
        const int c4 = t & 255, half = t >> 8;
        const float4* pp = (const float4*)(PPpart + (size_t)bh * NT_ * E_);
        float4 s = make_float4(0.f, 0.f, 0.f, 0.f);
        #pragma unroll 4
        for (int j = 0; j < 16; ++j) {
            float4 v = pp[(half * 16 + j) * 256 + c4];
            s.x += v.x; s.y += v.y; s.z += v.z; s.w += v.w;
        }
        ((float4*)&ph[half][0])[c4] = s;
    }
    __syncthreads();
    if (t < 256) {
        float4 p0 = ((const float4*)&ph[0][0])[t];
        float4 p1 = ((const float4*)&ph[1][0])[t];
        ((float4*)pooled)[t] = make_float4(p0.x + p1.x, p0.y + p1.y,
                                           p0.z + p1.z, p0.w + p1.w);
        float4 q = make_float4(0.f, 0.f, 0.f, 0.f);
        #pragma unroll
        for (int k2 = 0; k2 < 8; ++k2) {
            float4 v = ((const float4*)(P2p + ((size_t)k2 * B_ + b) * E_))[t];
            q.x += v.x; q.y += v.y; q.z += v.z; q.w += v.w;
        }
        ((float4*)pool2)[t] = q;
    }
    __syncthreads();

    // stage 2: Wv dots — 8 waves x 4 passes x 4 rg = 128 d
    const float4* pooled4 = (const float4*)pooled;
    const float4* pool24  = (const float4*)pool2;
    #pragma unroll
    for (int p = 0; p < 4; ++p) {
        const int d = p * 32 + w * 4 + rg;
        const float4* wvr = (const float4*)(Wv + (size_t)(h * D_ + d) * E_);
        float pA = 0.f, pV = 0.f;
        #pragma unroll 4
        for (int i = 0; i < 16; ++i) {
            float4 wv4 = wvr[cl + i * 16];
            float4 pa = pooled4[cl + i * 16];
            float4 pb = pool24[cl + i * 16];
            pA += wv4.x * pa.x + wv4.y * pa.y + wv4.z * pa.z + wv4.w * pa.w;
            pV += wv4.x * pb.x + wv4.y * pb.y + wv4.z * pb.z + wv4.w * pb.w;
        }
        #pragma unroll
        for (int off = 8; off; off >>= 1) {
            pA += __shfl_xor(pA, off);
            pV += __shfl_xor(pV, off);
        }
        if (cl == 0) { attA_s[d] = pA; attV_s[d] = pV; }
    }
    __syncthreads();

    // stage 3: epilogue
    if (t < 128) {
        int ci = 0;
        #pragma unroll
        for (int i = 0; i < 8; ++i) ci += mask[b * N_ + t + i * 128];
        float cf = (float)ci;
        #pragma unroll
        for (int off = 32; off; off >>= 1) cf += __shfl_down(cf, off);
        if ((t & 63) == 0) red2[t >> 6] = cf;
        const float ss = ssumg[bh];
        att[t] = attA_s[t] + ss * bv[h * D_ + t];
    }
    __syncthreads();
    if (t == 0) cnt_s = red2[0] + red2[1];
    if (t < MID_) {
        float a = bb[t];
        #pragma unroll 4
        for (int d2 = 0; d2 < D_; ++d2) a += att[d2] * Wb[t * D_ + d2];
        hv[t] = fmaxf(a, 0.f);
    }
    __syncthreads();
    if (t < 128) {
        float z = bl2[t];
        #pragma unroll
        for (int m = 0; m < MID_; ++m) z += hv[m] * Wl2[t * MID_ + m];
        float alphac = 1.f / (1.f + expf(-z));
        const float bvd = bv[h * D_ + t];
        float v2a = attV_s[t] / cnt_s + bvd;
        out[(size_t)b * E_ + h * D_ + t] =
            value1[(size_t)b * E_ + h * D_ + t] * v2a * alphac;
    }
}

// ---------------------------------------------------------------------------
extern "C" void kernel_launch(void* const* d_in, const int* in_sizes, int n_in,
                              void* d_out, int out_size, void* d_ws, size_t ws_size,
                              hipStream_t stream)
{
    const float* query  = (const float*)d_in[0];
    const float* key    = (const float*)d_in[1];
    const int*   mask   = (const int*)d_in[2];
    const float* value1 = (const float*)d_in[3];
    const float* value2 = (const float*)d_in[4];
    const float* Wq  = (const float*)d_in[5];
    const float* bq  = (const float*)d_in[6];
    const float* Wk  = (const float*)d_in[7];
    const float* bk  = (const float*)d_in[8];
    const float* Wv  = (const float*)d_in[9];
    const float* bv  = (const float*)d_in[10];
    const float* Wb  = (const float*)d_in[11];
    const float* bb  = (const float*)d_in[12];
    // d_in[13] = Wl, d_in[14] = bl: eliminated (softmax of uniform = mask/cnt)
    const float* Wl2 = (const float*)d_in[15];
    const float* bl2 = (const float*)d_in[16];
    float* out = (float*)d_out;

    // workspace layout (bytes), total ~35 MB
    char* ws = (char*)d_ws;
    const size_t SZ_PPP = (size_t)B_ * H_ * NT_ * E_ * 4;     // PPpart: 32 MB
    const size_t SZ_P2P = (size_t)8 * B_ * E_ * 4;            // P2p: 1 MB
    const size_t OFF_P2P = SZ_PPP;
    const size_t OFF_SS  = OFF_P2P + SZ_P2P;                  // ssum: 1 KB
    const size_t OFF_QB  = OFF_SS + 1024;                     // qb: 1 KB
    const size_t OFF_QK  = OFF_QB + 1024;                     // qk: 1 MB
    float* PPpart = (float*)(ws);
    float* P2p  = (float*)(ws + OFF_P2P);
    float* ssum = (float*)(ws + OFF_SS);
    float* qb   = (float*)(ws + OFF_QB);
    float* qk   = (float*)(ws + OFF_QK);

    // zero the atomic-accumulated region (P2p + ssum); PPpart is fully
    // overwritten by plain stores. stream-ordered, capture-safe
    hipMemsetAsync(ws + OFF_P2P, 0, SZ_P2P + 1024, stream);

    hipLaunchKernelGGL(k_qkproj, dim3(B_ * H_), dim3(256), 0, stream,
                       query, Wq, bq, Wk, bk, qk, qb);
    hipLaunchKernelGGL(k_main, dim3(2 * NT_ * B_), dim3(256), 0, stream,
                       key, qk, qb, PPpart, ssum, value2, mask, P2p);
    hipLaunchKernelGGL(k_tail, dim3(B_ * H_), dim3(512), 0, stream,
                       PPpart, P2p, ssum, mask, Wv, bv, Wb, bb, Wl2, bl2,
                       value1, out);
}

// Round 11
// 371.708 us; speedup vs baseline: 1.3619x; 1.1770x over previous
//
#include <hip/hip_runtime.h>

// Problem dims
#define B_  32
#define N_  1024
#define E_  1024
#define H_  8
#define D_  128
#define MID_ 64
#define NT_  32        // n-tiles for score+pool (32 rows each)
#define TR_  32        // rows per tile
#define NSP_ 32        // v2-pool split rows

// Journal (counter-backed lessons):
//  R3:  never replay a stream (FETCH doubles, no occupancy win).
//  R4:  never scale same-destination atomic writers (HBM RMW explosion).
//  R5:  VGPR=64 on a register-hungry kernel = spill to scratch.
//  R6:  __launch_bounds__(X,4) forces the 64-VGPR tier -> spill.
//  R7:  plain bounds -> scorepool 92us, VGPR 72, bytes ideal. BEST=372.
//  R8:  bigger subtiles -> VGPR tier slip; tiny pool splits waste blocks.
//  R9:  run live-set arithmetic BEFORE benching (204 VGPR disaster).
//  R10: score||pool interleave in one kernel degrades both (167 > 92+50);
//       0-for-2 on interleaving the barrier-heavy score kernel.
//  R11: the invisible ~280us residual = weight-stream x32 logical replay:
//       k_qkproj read Wq/Wk per (b,h) block (256 MB logical), k_tail read
//       Wv per bh block (128 MB logical). Fix: batch b INSIDE the block.
//       Wq: 16 MB, Wk: 4 MB (once), Wv: 16 MB.

// ---------------------------------------------------------------------------
// k_q: blocks [0,256): Qs = query@Wq^T + bq (batched: 8 b x 16 rows/block);
//      blocks [256,1280): v2 pooling (independent stream, overlaps).
//   qb[b,h] partials via 8 atomics/block (zeroed in memset).
// ---------------------------------------------------------------------------
__global__ __launch_bounds__(256) void k_q(
        const float* __restrict__ query, const float* __restrict__ Wq,
        const float* __restrict__ bq, const float* __restrict__ bk,
        float* __restrict__ Qs, float* __restrict__ qb,
        const float* __restrict__ value2, const int* __restrict__ mask,
        float* __restrict__ P2p)
{
    const int t = threadIdx.x;

    __shared__ __align__(16) float qsh[8 * E_];   // 32 KB: 8 query rows
    __shared__ __align__(16) float Qrow[8][16];   // [bb][r]
    __shared__ int rows[NSP_];
    __shared__ int nrows;

    if (blockIdx.x < 256) {
        // ---- Qs tile: b's b0..b0+7, Wq rows R..R+15 (within head h=rs>>3)
        const int bg = blockIdx.x >> 6;        // 0..3 -> b0 = bg*8
        const int rs = blockIdx.x & 63;        // 0..63 -> rows rs*16
        const int b0 = bg * 8;
        const int R  = rs * 16;
        const int h  = rs >> 3;

        // stage 8 query rows, coalesced (32 lanes per b-row)
        {
            const int bb = t >> 5, ln = t & 31;
            const float4* src = (const float4*)(query + (size_t)(b0 + bb) * E_);
            float4* dst = (float4*)(qsh + bb * E_);
            #pragma unroll
            for (int i = 0; i < 8; ++i) dst[ln + i * 32] = src[ln + i * 32];
        }
        __syncthreads();

        // thread = (r = t>>4 of 16 rows, cl = t&15 lanes per row)
        const int r = t >> 4, cl = t & 15;
        const int row = R + r;
        const float4* wr = (const float4*)(Wq + (size_t)row * E_);
        float4 wchunk[16];
        #pragma unroll
        for (int i = 0; i < 16; ++i) wchunk[i] = wr[cl + i * 16];

        const float bqv = bq[row];
        const float4* qsh4 = (const float4*)qsh;
        #pragma unroll
        for (int bb = 0; bb < 8; ++bb) {
            float acc = 0.f;
            #pragma unroll
            for (int i = 0; i < 16; ++i) {
                float4 q = qsh4[bb * 256 + cl + i * 16];
                acc += wchunk[i].x * q.x + wchunk[i].y * q.y
                     + wchunk[i].z * q.z + wchunk[i].w * q.w;
            }
            #pragma unroll
            for (int off = 8; off; off >>= 1) acc += __shfl_xor(acc, off);
            if (cl == 0) Qrow[bb][r] = acc + bqv;
        }
        __syncthreads();

        // qb partials: one thread per bb sums 16 rows
        if (t < 8) {
            float s = 0.f;
            #pragma unroll
            for (int rr = 0; rr < 16; ++rr) s += Qrow[t][rr] * bk[R + rr];
            atomicAdd(&qb[(b0 + t) * 8 + h], s);
        }
        // Qs store: 32 threads write 8 b x 4 float4
        if (t < 32) {
            const int bb = t >> 2, j = t & 3;
            ((float4*)(Qs + (size_t)(b0 + bb) * E_))[rs * 4 + j] =
                *(const float4*)&Qrow[bb][j * 4];
        }
    } else {
        // ---- v2 pooling: 32-row split; P2p[sp&7] partials
        const int pi = blockIdx.x - 256;        // [0,1024)
        const int b = pi & 31, sp = pi >> 5;
        const int e0 = t * 4;
        const int n0 = sp * NSP_;

        if (t == 0) nrows = 0;
        __syncthreads();
        if (t < NSP_) {
            if (mask[b * N_ + n0 + t]) {
                int i2 = atomicAdd(&nrows, 1);
                rows[i2] = t;
            }
        }
        __syncthreads();
        const int nr = nrows;

        float a0 = 0.f, a1 = 0.f, a2 = 0.f, a3 = 0.f;
        const float* vb = value2 + ((size_t)(b * N_ + n0)) * E_ + e0;
        #pragma unroll 4
        for (int i = 0; i < nr; ++i) {
            float4 v = *(const float4*)(vb + (size_t)rows[i] * E_);
            a0 += v.x; a1 += v.y; a2 += v.z; a3 += v.w;
        }
        float* dst = P2p + ((size_t)(sp & 7) * B_ + b) * E_ + e0;
        atomicAdd(dst + 0, a0); atomicAdd(dst + 1, a1);
        atomicAdd(dst + 2, a2); atomicAdd(dst + 3, a3);
    }
}

// ---------------------------------------------------------------------------
// k_k: qk[b,h,e] = sum_d Qs[b,h*D+d] * Wk[h*D+d,e], as LDS-tiled GEMM.
//   grid 256 = (h, 32-col tile); Wk read EXACTLY once (4 MB; was 128 MB
//   logical). QsL padded stride 132 floats -> conflict-free b-spread reads.
// ---------------------------------------------------------------------------
__global__ __launch_bounds__(256) void k_k(
        const float* __restrict__ Qs, const float* __restrict__ Wk,
        float* __restrict__ qk)
{
    const int h = blockIdx.x >> 5, ec = blockIdx.x & 31;
    const int t = threadIdx.x;

    __shared__ __align__(16) float QsL[32 * 132];   // padded, 16.9 KB
    __shared__ __align__(16) float WkL[128 * 32];   // 16 KB

    // stage Qs_h: 32 b x 128 d
    {
        const int b = t >> 3, j = t & 7;
        const float4* src = (const float4*)(Qs + (size_t)b * E_) + h * 32;
        float4* dst = (float4*)(QsL + b * 132);
        #pragma unroll
        for (int jj = 0; jj < 4; ++jj) dst[j + jj * 8] = src[j + jj * 8];
    }
    // stage Wk tile: 128 d x 32 e
    {
        #pragma unroll
        for (int jj = 0; jj < 4; ++jj) {
            const int idx = t + jj * 256;       // float4 index in tile
            const int d = idx >> 3, c = idx & 7;
            ((float4*)WkL)[idx] =
                ((const float4*)(Wk + (size_t)(h * D_ + d) * E_))[ec * 8 + c];
        }
    }
    __syncthreads();

    // compute: thread = (b = t>>3, eg = t&7) -> one float4 of qk
    const int b = t >> 3, eg = t & 7;
    float4 acc = make_float4(0.f, 0.f, 0.f, 0.f);
    const float* q = QsL + b * 132;
    const float4* wk4 = (const float4*)WkL;
    #pragma unroll 8
    for (int d = 0; d < D_; ++d) {
        float qd = q[d];
        float4 w = wk4[d * 8 + eg];
        acc.x += qd * w.x; acc.y += qd * w.y;
        acc.z += qd * w.z; acc.w += qd * w.w;
    }
    ((float4*)(qk + (size_t)(b * 8 + h) * E_))[ec * 8 + eg] = acc;
}

// ---------------------------------------------------------------------------
// k_main: R7 scorepool VERBATIM (92us, VGPR 72 proven). grid (NT_, B_).
// ---------------------------------------------------------------------------
__global__ __launch_bounds__(256) void k_main(
        const float* __restrict__ key, const float* __restrict__ qk,
        const float* __restrict__ qb, float* __restrict__ PPpart,
        float* __restrict__ ssum)
{
    const int tile = blockIdx.x, b = blockIdx.y;
    const int t = threadIdx.x;
    const int w = t >> 6, l = t & 63;

    __shared__ __align__(16) float part[4][4][8];   // [wave][r][h], 512 B
    __shared__ __align__(16) float sfin[4][8];      // [r][h], 128 B

    const float scale = 0.08838834764831845f;  // 1/sqrt(128)
    const float* keyb = key + ((size_t)b * N_ + (size_t)tile * TR_) * E_;
    const float qbv = (t < 32) ? qb[b * 8 + (t & 7)] : 0.f;

    float4 qkr[8];
    #pragma unroll
    for (int h = 0; h < H_; ++h)
        qkr[h] = ((const float4*)(qk + (size_t)(b * 8 + h) * E_))[t];

    float4 pacc[8];
    #pragma unroll
    for (int h = 0; h < 8; ++h) pacc[h] = make_float4(0.f, 0.f, 0.f, 0.f);

    float ts = 0.f;

    float4 kv[4];
    #pragma unroll
    for (int r = 0; r < 4; ++r)
        kv[r] = ((const float4*)(keyb + (size_t)r * E_))[t];

    for (int st = 0; st < 8; ++st) {
        #pragma unroll
        for (int r = 0; r < 4; ++r) {
            float p[8];
            #pragma unroll
            for (int h = 0; h < 8; ++h)
                p[h] = qkr[h].x * kv[r].x + qkr[h].y * kv[r].y
                     + qkr[h].z * kv[r].z + qkr[h].w * kv[r].w;
            #pragma unroll
            for (int off = 32; off; off >>= 1) {
                #pragma unroll
                for (int h = 0; h < 8; ++h)
                    p[h] += __shfl_xor(p[h], off);
            }
            if (l == 0) {
                *(float4*)&part[w][r][0] = make_float4(p[0], p[1], p[2], p[3]);
                *(float4*)&part[w][r][4] = make_float4(p[4], p[5], p[6], p[7]);
            }
        }
        float4 kn[4];
        if (st < 7) {
            #pragma unroll
            for (int r = 0; r < 4; ++r)
                kn[r] = ((const float4*)(keyb
                            + (size_t)((st + 1) * 4 + r) * E_))[t];
        }
        __syncthreads();
        if (t < 32) {
            const int r = t >> 3, h = t & 7;
            float s = (part[0][r][h] + part[1][r][h]
                     + part[2][r][h] + part[3][r][h] + qbv) * scale;
            sfin[r][h] = s;
            ts += s;
        }
        __syncthreads();
        #pragma unroll
        for (int r = 0; r < 4; ++r) {
            const float4 k4 = kv[r];
            const float4 sA = *(const float4*)&sfin[r][0];
            const float4 sB = *(const float4*)&sfin[r][4];
            pacc[0].x += sA.x * k4.x; pacc[0].y += sA.x * k4.y;
            pacc[0].z += sA.x * k4.z; pacc[0].w += sA.x * k4.w;
            pacc[1].x += sA.y * k4.x; pacc[1].y += sA.y * k4.y;
            pacc[1].z += sA.y * k4.z; pacc[1].w += sA.y * k4.w;
            pacc[2].x += sA.z * k4.x; pacc[2].y += sA.z * k4.y;
            pacc[2].z += sA.z * k4.z; pacc[2].w += sA.z * k4.w;
            pacc[3].x += sA.w * k4.x; pacc[3].y += sA.w * k4.y;
            pacc[3].z += sA.w * k4.z; pacc[3].w += sA.w * k4.w;
            pacc[4].x += sB.x * k4.x; pacc[4].y += sB.x * k4.y;
            pacc[4].z += sB.x * k4.z; pacc[4].w += sB.x * k4.w;
            pacc[5].x += sB.y * k4.x; pacc[5].y += sB.y * k4.y;
            pacc[5].z += sB.y * k4.z; pacc[5].w += sB.y * k4.w;
            pacc[6].x += sB.z * k4.x; pacc[6].y += sB.z * k4.y;
            pacc[6].z += sB.z * k4.z; pacc[6].w += sB.z * k4.w;
            pacc[7].x += sB.w * k4.x; pacc[7].y += sB.w * k4.y;
            pacc[7].z += sB.w * k4.z; pacc[7].w += sB.w * k4.w;
        }
        #pragma unroll
        for (int r = 0; r < 4; ++r) kv[r] = kn[r];
    }

    if (t < 32) {
        float v = ts;
        v += __shfl_xor(v, 8);
        v += __shfl_xor(v, 16);
        if (l < 8) atomicAdd(&ssum[b * 8 + l], v);
    }

    #pragma unroll
    for (int h = 0; h < 8; ++h) {
        ((float4*)(PPpart
            + (((size_t)(b * H_ + h)) * NT_ + tile) * E_))[t] = pacc[h];
    }
}

// ---------------------------------------------------------------------------
// k_red: pooled[bh] = sum_tl PPpart[bh,tl]; blocks bh<32 also fold P2p->pool2.
// ---------------------------------------------------------------------------
__global__ __launch_bounds__(256) void k_red(
        const float* __restrict__ PPpart, const float* __restrict__ P2p,
        float* __restrict__ pooled, float* __restrict__ pool2)
{
    const int bh = blockIdx.x;
    const int t = threadIdx.x;
    const float4* pp = (const float4*)(PPpart + (size_t)bh * NT_ * E_);
    float4 s = make_float4(0.f, 0.f, 0.f, 0.f);
    #pragma unroll 8
    for (int tl = 0; tl < NT_; ++tl) {
        float4 v = pp[tl * 256 + t];
        s.x += v.x; s.y += v.y; s.z += v.z; s.w += v.w;
    }
    ((float4*)(pooled + (size_t)bh * E_))[t] = s;

    if (bh < B_) {
        float4 q = make_float4(0.f, 0.f, 0.f, 0.f);
        #pragma unroll
        for (int k2 = 0; k2 < 8; ++k2) {
            float4 v = ((const float4*)(P2p + ((size_t)k2 * B_ + bh) * E_))[t];
            q.x += v.x; q.y += v.y; q.z += v.z; q.w += v.w;
        }
        ((float4*)(pool2 + (size_t)bh * E_))[t] = q;
    }
}

// ---------------------------------------------------------------------------
// k_att2: attA/attV[b,h,d] = pooled[b,h]/pool2[b] · Wv_row(h*D+d), batched
//   over 8 b's per block so Wv logical traffic = 16 MB (was 128 MB).
// grid 256 = (h:8, dc:8 of 16 d-rows, bq:4 of 8 b's); LDS 64 KB.
// ---------------------------------------------------------------------------
__global__ __launch_bounds__(256) void k_att2(
        const float* __restrict__ pooled, const float* __restrict__ pool2,
        const float* __restrict__ Wv,
        float* __restrict__ attA, float* __restrict__ attV)
{
    const int h  = blockIdx.x >> 5;
    const int dc = (blockIdx.x >> 2) & 7;
    const int bq = blockIdx.x & 3;
    const int t = threadIdx.x;

    __shared__ __align__(16) float pL[8 * E_];    // 32 KB
    __shared__ __align__(16) float p2L[8 * E_];   // 32 KB

    // stage pooled/pool2 for this block's 8 b's
    {
        const int bb = t >> 5, ln = t & 31;
        const int b = bq * 8 + bb;
        const float4* sp = (const float4*)(pooled + (size_t)(b * 8 + h) * E_);
        const float4* s2 = (const float4*)(pool2 + (size_t)b * E_);
        float4* dp = (float4*)(pL + bb * E_);
        float4* d2 = (float4*)(p2L + bb * E_);
        #pragma unroll
        for (int i = 0; i < 8; ++i) {
            dp[ln + i * 32] = sp[ln + i * 32];
            d2[ln + i * 32] = s2[ln + i * 32];
        }
    }
    __syncthreads();

    // thread = (r = t>>4 of 16 d-rows, cl = t&15)
    const int r = t >> 4, cl = t & 15;
    const int d = dc * 16 + r;
    const float4* wvr = (const float4*)(Wv + (size_t)(h * D_ + d) * E_);
    const float4* pL4 = (const float4*)pL;
    const float4* p2L4 = (const float4*)p2L;

    float aA[8] = {}, aV[8] = {};
    #pragma unroll 4
    for (int i = 0; i < 16; ++i) {
        float4 w = wvr[cl + i * 16];
        #pragma unroll
        for (int bb = 0; bb < 8; ++bb) {
            float4 pa = pL4[bb * 256 + cl + i * 16];
            float4 pb = p2L4[bb * 256 + cl + i * 16];
            aA[bb] += w.x * pa.x + w.y * pa.y + w.z * pa.z + w.w * pa.w;
            aV[bb] += w.x * pb.x + w.y * pb.y + w.z * pb.z + w.w * pb.w;
        }
    }
    #pragma unroll
    for (int off = 8; off; off >>= 1) {
        #pragma unroll
        for (int bb = 0; bb < 8; ++bb) {
            aA[bb] += __shfl_xor(aA[bb], off);
            aV[bb] += __shfl_xor(aV[bb], off);
        }
    }
    if (cl == 0) {
        #pragma unroll
        for (int bb = 0; bb < 8; ++bb) {
            const int bh = (bq * 8 + bb) * 8 + h;
            attA[(size_t)bh * D_ + d] = aA[bb];
            attV[(size_t)bh * D_ + d] = aV[bb];
        }
    }
}

// ---------------------------------------------------------------------------
// k_final (light epilogue). per (b,h), 128 threads (t = d)
// ---------------------------------------------------------------------------
__global__ __launch_bounds__(128) void k_final(
        const float* __restrict__ attA, const float* __restrict__ attV,
        const float* __restrict__ ssumg, const int* __restrict__ mask,
        const float* __restrict__ bv, const float* __restrict__ Wb,
        const float* __restrict__ bb, const float* __restrict__ Wl2,
        const float* __restrict__ bl2, const float* __restrict__ value1,
        float* __restrict__ out)
{
    const int bh = blockIdx.x, b = bh >> 3, h = bh & 7;
    const int t = threadIdx.x;

    __shared__ float att[D_];
    __shared__ float hv[MID_];
    __shared__ float red2[2];
    __shared__ float cnt_s;

    int ci = 0;
    #pragma unroll
    for (int i = 0; i < 8; ++i) ci += mask[b * N_ + t + i * 128];
    float cf = (float)ci;
    #pragma unroll
    for (int off = 32; off; off >>= 1) cf += __shfl_down(cf, off);
    if ((t & 63) == 0) red2[t >> 6] = cf;

    const float ss = ssumg[bh];
    att[t] = attA[(size_t)bh * D_ + t] + ss * bv[h * D_ + t];
    __syncthreads();
    if (t == 0) cnt_s = red2[0] + red2[1];
    if (t < MID_) {
        float a = bb[t];
        #pragma unroll 4
        for (int d2 = 0; d2 < D_; ++d2) a += att[d2] * Wb[t * D_ + d2];
        hv[t] = fmaxf(a, 0.f);
    }
    __syncthreads();

    float z = bl2[t];
    #pragma unroll
    for (int m = 0; m < MID_; ++m) z += hv[m] * Wl2[t * MID_ + m];
    float alphac = 1.f / (1.f + expf(-z));
    const float bvd = bv[h * D_ + t];
    float v2a = attV[(size_t)bh * D_ + t] / cnt_s + bvd;
    out[(size_t)b * E_ + h * D_ + t] =
        value1[(size_t)b * E_ + h * D_ + t] * v2a * alphac;
}

// ---------------------------------------------------------------------------
extern "C" void kernel_launch(void* const* d_in, const int* in_sizes, int n_in,
                              void* d_out, int out_size, void* d_ws, size_t ws_size,
                              hipStream_t stream)
{
    const float* query  = (const float*)d_in[0];
    const float* key    = (const float*)d_in[1];
    const int*   mask   = (const int*)d_in[2];
    const float* value1 = (const float*)d_in[3];
    const float* value2 = (const float*)d_in[4];
    const float* Wq  = (const float*)d_in[5];
    const float* bq  = (const float*)d_in[6];
    const float* Wk  = (const float*)d_in[7];
    const float* bk  = (const float*)d_in[8];
    const float* Wv  = (const float*)d_in[9];
    const float* bv  = (const float*)d_in[10];
    const float* Wb  = (const float*)d_in[11];
    const float* bb  = (const float*)d_in[12];
    // d_in[13] = Wl, d_in[14] = bl: eliminated (softmax of uniform = mask/cnt)
    const float* Wl2 = (const float*)d_in[15];
    const float* bl2 = (const float*)d_in[16];
    float* out = (float*)d_out;

    // workspace layout (bytes), ~36 MB
    char* ws = (char*)d_ws;
    const size_t SZ_PPP = (size_t)B_ * H_ * NT_ * E_ * 4;     // PPpart: 32 MB
    const size_t SZ_P2P = (size_t)8 * B_ * E_ * 4;            // P2p: 1 MB
    const size_t OFF_P2P = SZ_PPP;
    const size_t OFF_SS  = OFF_P2P + SZ_P2P;                  // ssum: 1 KB
    const size_t OFF_QB  = OFF_SS + 1024;                     // qb: 1 KB
    const size_t OFF_QS  = OFF_QB + 1024;                     // Qs: 128 KB
    const size_t OFF_QK  = OFF_QS + (size_t)B_ * E_ * 4;      // qk: 1 MB
    const size_t OFF_PL  = OFF_QK + (size_t)B_ * H_ * E_ * 4; // pooled: 1 MB
    const size_t OFF_P2  = OFF_PL + (size_t)B_ * H_ * E_ * 4; // pool2: 128 KB
    const size_t OFF_AA  = OFF_P2 + (size_t)B_ * E_ * 4;      // attA: 128 KB
    const size_t OFF_AV  = OFF_AA + (size_t)B_ * H_ * D_ * 4; // attV: 128 KB
    float* PPpart = (float*)(ws);
    float* P2p    = (float*)(ws + OFF_P2P);
    float* ssum   = (float*)(ws + OFF_SS);
    float* qb     = (float*)(ws + OFF_QB);
    float* Qs     = (float*)(ws + OFF_QS);
    float* qk     = (float*)(ws + OFF_QK);
    float* pooled = (float*)(ws + OFF_PL);
    float* pool2  = (float*)(ws + OFF_P2);
    float* attA   = (float*)(ws + OFF_AA);
    float* attV   = (float*)(ws + OFF_AV);

    // zero atomic-accumulated regions: P2p + ssum + qb (contiguous)
    hipMemsetAsync(ws + OFF_P2P, 0, SZ_P2P + 2048, stream);

    hipLaunchKernelGGL(k_q, dim3(256 + NT_ * B_), dim3(256), 0, stream,
                       query, Wq, bq, bk, Qs, qb, value2, mask, P2p);
    hipLaunchKernelGGL(k_k, dim3(256), dim3(256), 0, stream,
                       Qs, Wk, qk);
    hipLaunchKernelGGL(k_main, dim3(NT_, B_), dim3(256), 0, stream,
                       key, qk, qb, PPpart, ssum);
    hipLaunchKernelGGL(k_red, dim3(B_ * H_), dim3(256), 0, stream,
                       PPpart, P2p, pooled, pool2);
    hipLaunchKernelGGL(k_att2, dim3(256), dim3(256), 0, stream,
                       pooled, pool2, Wv, attA, attV);
    hipLaunchKernelGGL(k_final, dim3(B_ * H_), dim3(128), 0, stream,
                       attA, attV, ssum, mask, bv, Wb, bb, Wl2, bl2,
                       value1, out);
}